// Round 1
// baseline (2093.418 us; speedup 1.0000x reference)
//
#include <hip/hip_runtime.h>
#include <cmath>

#define HID 128
#define TILE_E 32
#define TILE_N 32

__device__ __forceinline__ float sigmoid_f(float v) { return 1.0f / (1.0f + expf(-v)); }
__device__ __forceinline__ float silu_f(float v)    { return v / (1.0f + expf(-v)); }

// ---------------------------------------------------------------------------
// Edge kernel: per edge e (row=src j, col=dst i):
//   msg = [h[col], h[row], dist]                       (257)
//   t1  = silu(msg @ We1 + be1)                        (128)
//   m   = silu(t1 @ We2 + be2)                         (128)
//   g   = sigmoid(m . Wg + bg);  m *= g
//   atomicAdd m into m_aggr[col]
//   cw  = silu(m @ Wc1 + bc1) . Wc2 + bc2              (scalar)
//   atomicAdd coord_diff * cw into coord_aggr[col]
// 32 edges per 256-thread block; msg matrix staged in LDS.
// ---------------------------------------------------------------------------
__global__ __launch_bounds__(256) void egnn_edge_kernel(
    const float* __restrict__ h, const float* __restrict__ x,
    const int* __restrict__ ei, int E,
    const float* __restrict__ We1, const float* __restrict__ be1,
    const float* __restrict__ We2, const float* __restrict__ be2,
    const float* __restrict__ Wg,  const float* __restrict__ bg,
    const float* __restrict__ Wc1, const float* __restrict__ bc1,
    const float* __restrict__ Wc2, const float* __restrict__ bc2,
    float* __restrict__ m_aggr, float* __restrict__ coord_aggr)
{
    __shared__ float s_msg[TILE_E][260];   // 257 + pad to keep float4 alignment (260*4 % 16 == 0)
    __shared__ float s_t[TILE_E][HID];
    __shared__ float s_cd[TILE_E][3];
    __shared__ float s_scl[TILE_E];
    __shared__ float s_wg[HID];
    __shared__ float s_wc2[HID];
    __shared__ int   s_row[TILE_E];
    __shared__ int   s_col[TILE_E];
    float* s_m = &s_msg[0][0];             // reused as [TILE_E][HID] after layer 1

    const int tid = threadIdx.x;
    const int e0  = blockIdx.x * TILE_E;
    const int ne  = min(TILE_E, E - e0);

    if (tid < TILE_E) {
        int eg = e0 + ((tid < ne) ? tid : 0);
        s_row[tid] = ei[eg];
        s_col[tid] = ei[E + eg];
    }
    if (tid < HID) {                       // stage gate / coord-head weight vectors
        s_wg[tid]  = Wg[tid];
        s_wc2[tid] = Wc2[tid];
    }
    __syncthreads();

    if (tid < TILE_E) {
        int r = s_row[tid], c = s_col[tid];
        float dx = x[c * 3 + 0] - x[r * 3 + 0];
        float dy = x[c * 3 + 1] - x[r * 3 + 1];
        float dz = x[c * 3 + 2] - x[r * 3 + 2];
        s_cd[tid][0] = dx; s_cd[tid][1] = dy; s_cd[tid][2] = dz;
        s_msg[tid][256] = sqrtf(dx * dx + dy * dy + dz * dz);
    }
    for (int idx = tid; idx < TILE_E * 256; idx += 256) {
        int e = idx >> 8;
        int k = idx & 255;
        s_msg[e][k] = (k < HID) ? h[(size_t)s_col[e] * HID + k]
                                : h[(size_t)s_row[e] * HID + (k - HID)];
    }
    __syncthreads();

    const int f    = tid & (HID - 1);
    const int half = tid >> 7;             // 0 or 1
    const int EPT  = TILE_E / 2;           // 16 edges per thread
    const int eb   = half * EPT;

    float acc[TILE_E / 2];

    // ---- layer 1: msg @ We1 + be1, silu -> s_t ----
    {
        float b = be1[f];
        #pragma unroll
        for (int i = 0; i < EPT; ++i) acc[i] = b;
        for (int k = 0; k < 256; k += 4) {
            float w0 = We1[(k + 0) * HID + f];
            float w1 = We1[(k + 1) * HID + f];
            float w2 = We1[(k + 2) * HID + f];
            float w3 = We1[(k + 3) * HID + f];
            #pragma unroll
            for (int i = 0; i < EPT; ++i) {
                float4 v = *(const float4*)&s_msg[eb + i][k];
                acc[i] += v.x * w0 + v.y * w1 + v.z * w2 + v.w * w3;
            }
        }
        float wlast = We1[256 * HID + f];
        #pragma unroll
        for (int i = 0; i < EPT; ++i) {
            acc[i] += s_msg[eb + i][256] * wlast;
            s_t[eb + i][f] = silu_f(acc[i]);
        }
    }
    __syncthreads();

    // ---- layer 2: s_t @ We2 + be2, silu -> s_m (aliases s_msg, dead now) ----
    {
        float b = be2[f];
        #pragma unroll
        for (int i = 0; i < EPT; ++i) acc[i] = b;
        for (int k = 0; k < HID; k += 4) {
            float w0 = We2[(k + 0) * HID + f];
            float w1 = We2[(k + 1) * HID + f];
            float w2 = We2[(k + 2) * HID + f];
            float w3 = We2[(k + 3) * HID + f];
            #pragma unroll
            for (int i = 0; i < EPT; ++i) {
                float4 v = *(const float4*)&s_t[eb + i][k];
                acc[i] += v.x * w0 + v.y * w1 + v.z * w2 + v.w * w3;
            }
        }
        #pragma unroll
        for (int i = 0; i < EPT; ++i)
            s_m[(eb + i) * HID + f] = silu_f(acc[i]);
    }
    __syncthreads();

    // ---- gate: sigmoid(m . Wg + bg) per edge (lane-rotated to dodge bank conflicts) ----
    if (tid < TILE_E) {
        float g = bg[0];
        #pragma unroll 4
        for (int kk = 0; kk < HID; ++kk) {
            int k = (kk + tid) & (HID - 1);
            g += s_m[tid * HID + k] * s_wg[k];
        }
        s_scl[tid] = sigmoid_f(g);
    }
    __syncthreads();

    // ---- apply gate + scatter-add m_aggr ----
    #pragma unroll
    for (int i = 0; i < EPT; ++i) {
        int e = eb + i;
        float mg = s_m[e * HID + f] * s_scl[e];
        s_m[e * HID + f] = mg;
        if (e < ne) atomicAdd(&m_aggr[(size_t)s_col[e] * HID + f], mg);
    }
    __syncthreads();

    // ---- coord head layer 1: silu(m @ Wc1 + bc1) -> s_t ----
    {
        float b = bc1[f];
        #pragma unroll
        for (int i = 0; i < EPT; ++i) acc[i] = b;
        for (int k = 0; k < HID; k += 4) {
            float w0 = Wc1[(k + 0) * HID + f];
            float w1 = Wc1[(k + 1) * HID + f];
            float w2 = Wc1[(k + 2) * HID + f];
            float w3 = Wc1[(k + 3) * HID + f];
            #pragma unroll
            for (int i = 0; i < EPT; ++i) {
                float4 v = *(const float4*)&s_m[(eb + i) * HID + k];
                acc[i] += v.x * w0 + v.y * w1 + v.z * w2 + v.w * w3;
            }
        }
        #pragma unroll
        for (int i = 0; i < EPT; ++i)
            s_t[eb + i][f] = silu_f(acc[i]);
    }
    __syncthreads();

    // ---- coord head layer 2 (dot) + coord scatter ----
    if (tid < ne) {
        float cw = bc2[0];
        #pragma unroll 4
        for (int kk = 0; kk < HID; ++kk) {
            int k = (kk + tid) & (HID - 1);
            cw += s_t[tid][k] * s_wc2[k];
        }
        int c = s_col[tid];
        atomicAdd(&coord_aggr[c * 3 + 0], s_cd[tid][0] * cw);
        atomicAdd(&coord_aggr[c * 3 + 1], s_cd[tid][1] * cw);
        atomicAdd(&coord_aggr[c * 3 + 2], s_cd[tid][2] * cw);
    }
}

// ---------------------------------------------------------------------------
// Node kernel: h_out = h + silu([h, m_aggr] @ Wn1 + bn1) @ Wn2 + bn2
//              x_out = x + coord_aggr
// ---------------------------------------------------------------------------
__global__ __launch_bounds__(256) void egnn_node_kernel(
    const float* __restrict__ h, const float* __restrict__ x,
    const float* __restrict__ m_aggr, const float* __restrict__ coord_aggr,
    const float* __restrict__ Wn1, const float* __restrict__ bn1,
    const float* __restrict__ Wn2, const float* __restrict__ bn2,
    float* __restrict__ h_out, float* __restrict__ x_out, int N)
{
    __shared__ float s_in[TILE_N][256];
    __shared__ float s_t[TILE_N][HID];

    const int tid = threadIdx.x;
    const int n0  = blockIdx.x * TILE_N;
    const int nn  = min(TILE_N, N - n0);

    // x_out (independent, do first)
    if (tid < TILE_N * 3) {
        int n = tid / 3, d = tid % 3;
        if (n < nn) {
            size_t gi = (size_t)(n0 + n) * 3 + d;
            x_out[gi] = x[gi] + coord_aggr[gi];
        }
    }

    for (int idx = tid; idx < TILE_N * 256; idx += 256) {
        int n = idx >> 8, k = idx & 255;
        int ng = n0 + ((n < nn) ? n : 0);
        s_in[n][k] = (k < HID) ? h[(size_t)ng * HID + k]
                               : m_aggr[(size_t)ng * HID + (k - HID)];
    }
    __syncthreads();

    const int f    = tid & (HID - 1);
    const int half = tid >> 7;
    const int NPT  = TILE_N / 2;
    const int nb   = half * NPT;
    float acc[TILE_N / 2];

    // ---- node layer 1: [h, m_aggr] @ Wn1 + bn1, silu -> s_t ----
    {
        float b = bn1[f];
        #pragma unroll
        for (int i = 0; i < NPT; ++i) acc[i] = b;
        for (int k = 0; k < 256; k += 4) {
            float w0 = Wn1[(k + 0) * HID + f];
            float w1 = Wn1[(k + 1) * HID + f];
            float w2 = Wn1[(k + 2) * HID + f];
            float w3 = Wn1[(k + 3) * HID + f];
            #pragma unroll
            for (int i = 0; i < NPT; ++i) {
                float4 v = *(const float4*)&s_in[nb + i][k];
                acc[i] += v.x * w0 + v.y * w1 + v.z * w2 + v.w * w3;
            }
        }
        #pragma unroll
        for (int i = 0; i < NPT; ++i)
            s_t[nb + i][f] = silu_f(acc[i]);
    }
    __syncthreads();

    // ---- node layer 2 + residual ----
    {
        float b = bn2[f];
        #pragma unroll
        for (int i = 0; i < NPT; ++i) acc[i] = b;
        for (int k = 0; k < HID; k += 4) {
            float w0 = Wn2[(k + 0) * HID + f];
            float w1 = Wn2[(k + 1) * HID + f];
            float w2 = Wn2[(k + 2) * HID + f];
            float w3 = Wn2[(k + 3) * HID + f];
            #pragma unroll
            for (int i = 0; i < NPT; ++i) {
                float4 v = *(const float4*)&s_t[nb + i][k];
                acc[i] += v.x * w0 + v.y * w1 + v.z * w2 + v.w * w3;
            }
        }
        #pragma unroll
        for (int i = 0; i < NPT; ++i) {
            int n = nb + i;
            if (n < nn)
                h_out[(size_t)(n0 + n) * HID + f] = s_in[n][f] + acc[i];
        }
    }
}

extern "C" void kernel_launch(void* const* d_in, const int* in_sizes, int n_in,
                              void* d_out, int out_size, void* d_ws, size_t ws_size,
                              hipStream_t stream) {
    const float* h   = (const float*)d_in[0];
    const float* x   = (const float*)d_in[1];
    const int*   ei  = (const int*)d_in[2];
    const float* We1 = (const float*)d_in[3];
    const float* be1 = (const float*)d_in[4];
    const float* We2 = (const float*)d_in[5];
    const float* be2 = (const float*)d_in[6];
    const float* Wg  = (const float*)d_in[7];
    const float* bg  = (const float*)d_in[8];
    const float* Wn1 = (const float*)d_in[9];
    const float* bn1 = (const float*)d_in[10];
    const float* Wn2 = (const float*)d_in[11];
    const float* bn2 = (const float*)d_in[12];
    const float* Wc1 = (const float*)d_in[13];
    const float* bc1 = (const float*)d_in[14];
    const float* Wc2 = (const float*)d_in[15];
    const float* bc2 = (const float*)d_in[16];

    const int N = in_sizes[0] / HID;
    const int E = in_sizes[2] / 2;

    float* m_aggr     = (float*)d_ws;
    float* coord_aggr = m_aggr + (size_t)N * HID;

    hipMemsetAsync(d_ws, 0, (size_t)N * (HID + 3) * sizeof(float), stream);

    float* h_out = (float*)d_out;
    float* x_out = h_out + (size_t)N * HID;

    dim3 blk(256);
    egnn_edge_kernel<<<dim3((E + TILE_E - 1) / TILE_E), blk, 0, stream>>>(
        h, x, ei, E, We1, be1, We2, be2, Wg, bg, Wc1, bc1, Wc2, bc2,
        m_aggr, coord_aggr);
    egnn_node_kernel<<<dim3((N + TILE_N - 1) / TILE_N), blk, 0, stream>>>(
        h, x, m_aggr, coord_aggr, Wn1, bn1, Wn2, bn2, h_out, x_out, N);
}

// Round 2
// 661.219 us; speedup vs baseline: 3.1660x; 3.1660x over previous
//
#include <hip/hip_runtime.h>
#include <cmath>

#define HID 128
#define TILE_N 32

typedef __attribute__((ext_vector_type(8))) short bf16x8;
typedef __attribute__((ext_vector_type(4))) float f32x4;

__device__ __forceinline__ float bf2f(unsigned short u) {
    union { unsigned int i; float f; } c; c.i = ((unsigned int)u) << 16; return c.f;
}
__device__ __forceinline__ unsigned short f2bf(float f) {
    union { float f; unsigned int i; } c; c.f = f;
    unsigned int r = c.i + 0x7fffu + ((c.i >> 16) & 1u);
    return (unsigned short)(r >> 16);
}
__device__ __forceinline__ float silu_f(float v)    { return v / (1.0f + expf(-v)); }
__device__ __forceinline__ float sigmoid_f(float v) { return 1.0f / (1.0f + expf(-v)); }

// ---------------------------------------------------------------------------
// Weight prep: rearrange We1 (256 rows), We2, Wc1 into MFMA-fragment-major
// bf16 layout: dst[((nt*KC + kc)*64 + lane)*8 + j] = W[k][nt*16 + (lane&15)]
// with k = kc*32 + (lane>>4)*4 + (j&3) + (j>>2)*16.
// ---------------------------------------------------------------------------
__global__ __launch_bounds__(256) void egnn_prep(
    const float* __restrict__ We1, const float* __restrict__ We2,
    const float* __restrict__ Wc1,
    short* __restrict__ We1p, short* __restrict__ We2p, short* __restrict__ Wc1p)
{
    int t = blockIdx.x * 256 + threadIdx.x;     // 8192 threads total
    int frag = t >> 6, lane = t & 63;
    const float* W; short* dst; int KC, nt, kc;
    if (frag < 64)      { W = We1; dst = We1p; KC = 8; int f = frag;      nt = f >> 3; kc = f & 7; }
    else if (frag < 96) { W = We2; dst = We2p; KC = 4; int f = frag - 64; nt = f >> 2; kc = f & 3; }
    else                { W = Wc1; dst = Wc1p; KC = 4; int f = frag - 96; nt = f >> 2; kc = f & 3; }
    int n = nt * 16 + (lane & 15);
    short* d = dst + (((size_t)nt * KC + kc) * 64 + lane) * 8;
    #pragma unroll
    for (int j = 0; j < 8; ++j) {
        int k = kc * 32 + ((lane >> 4) << 2) + (j & 3) + ((j >> 2) << 4);
        d[j] = (short)f2bf(W[(size_t)k * HID + n]);
    }
}

// ---------------------------------------------------------------------------
// Shared MFMA layer for K=128: sDst = silu(sSrc @ Wp + bias), both act
// buffers are [64][128] bf16 with byte-XOR swizzle ((row&7)<<4).
// ---------------------------------------------------------------------------
__device__ __forceinline__ void mfma_layer128(
    const short* __restrict__ sSrc, const short* __restrict__ Wp,
    const float* __restrict__ bias, short* __restrict__ sDst,
    int w, int lane)
{
    const int l15 = lane & 15, g = lane >> 4;
    f32x4 acc[4][2];
    float b0 = bias[w * 32 + l15], b1 = bias[w * 32 + 16 + l15];
    #pragma unroll
    for (int rf = 0; rf < 4; ++rf) {
        acc[rf][0] = f32x4{b0, b0, b0, b0};
        acc[rf][1] = f32x4{b1, b1, b1, b1};
    }
    #pragma unroll
    for (int kc = 0; kc < 4; ++kc) {
        bf16x8 B0 = *(const bf16x8*)(Wp + (((size_t)(2 * w) * 4 + kc) * 64 + lane) * 8);
        bf16x8 B1 = *(const bf16x8*)(Wp + (((size_t)(2 * w + 1) * 4 + kc) * 64 + lane) * 8);
        #pragma unroll
        for (int rf = 0; rf < 4; ++rf) {
            int e = rf * 16 + l15, sw = (e & 7) << 4;
            const char* pr = (const char*)sSrc + e * 256;
            int kb = kc * 64 + g * 8;
            uint2 lo = *(const uint2*)(pr + ((kb     ) ^ sw));
            uint2 hi = *(const uint2*)(pr + ((kb + 32) ^ sw));
            bf16x8 a; ((uint2*)&a)[0] = lo; ((uint2*)&a)[1] = hi;
            acc[rf][0] = __builtin_amdgcn_mfma_f32_16x16x32_bf16(a, B0, acc[rf][0], 0, 0, 0);
            acc[rf][1] = __builtin_amdgcn_mfma_f32_16x16x32_bf16(a, B1, acc[rf][1], 0, 0, 0);
        }
    }
    #pragma unroll
    for (int rf = 0; rf < 4; ++rf)
    #pragma unroll
    for (int r = 0; r < 4; ++r) {
        int e = rf * 16 + g * 4 + r, sw = (e & 7) << 4;
        char* pd = (char*)sDst + e * 256;
        *(unsigned short*)(pd + ((2 * (w * 32 + l15)) ^ sw))      = f2bf(silu_f(acc[rf][0][r]));
        *(unsigned short*)(pd + ((2 * (w * 32 + 16 + l15)) ^ sw)) = f2bf(silu_f(acc[rf][1][r]));
    }
}

// per-edge dot(act_row, wvec): 4 lanes per edge, shfl reduce
__device__ __forceinline__ float dot128(const short* __restrict__ sAct,
                                        const float* __restrict__ wvec,
                                        int w, int lane)
{
    int e = w * 16 + (lane & 15), g = lane >> 4, sw = (e & 7) << 4;
    const char* pr = (const char*)sAct + e * 256;
    float sum = 0.f;
    #pragma unroll
    for (int j = 0; j < 4; ++j) {
        uint4 v = *(const uint4*)(pr + ((g * 64 + j * 16) ^ sw));
        const float* wv = wvec + g * 32 + j * 8;
        sum += bf2f((unsigned short)(v.x      )) * wv[0];
        sum += bf2f((unsigned short)(v.x >> 16)) * wv[1];
        sum += bf2f((unsigned short)(v.y      )) * wv[2];
        sum += bf2f((unsigned short)(v.y >> 16)) * wv[3];
        sum += bf2f((unsigned short)(v.z      )) * wv[4];
        sum += bf2f((unsigned short)(v.z >> 16)) * wv[5];
        sum += bf2f((unsigned short)(v.w      )) * wv[6];
        sum += bf2f((unsigned short)(v.w >> 16)) * wv[7];
    }
    sum += __shfl_xor(sum, 16, 64);
    sum += __shfl_xor(sum, 32, 64);
    return sum;
}

// ---------------------------------------------------------------------------
// Edge kernel: 64 edges/block, 4 waves, wave w owns output cols [32w,32w+32).
// ---------------------------------------------------------------------------
__global__ __launch_bounds__(256) void egnn_edge_mfma(
    const float* __restrict__ h, const float* __restrict__ x,
    const int* __restrict__ ei, int E,
    const short* __restrict__ We1p, const float* __restrict__ We1,
    const float* __restrict__ be1,
    const short* __restrict__ We2p, const float* __restrict__ be2,
    const float* __restrict__ Wg, const float* __restrict__ bg,
    const short* __restrict__ Wc1p, const float* __restrict__ bc1,
    const float* __restrict__ Wc2, const float* __restrict__ bc2,
    float* __restrict__ m_aggr, float* __restrict__ coord_aggr)
{
    __shared__ short sA[64 * 256];   // R1: A1 tile (32KB); later [0:16K)=act2, [16K:32K)=act2g
    __shared__ short sB[64 * 128];   // R2: act1, then act3 (16KB)
    __shared__ float s_cd[64][3];
    __shared__ float s_dist[64];
    __shared__ float s_gate[64];
    __shared__ int   s_col[64], s_row[64];
    __shared__ float s_wg[128], s_wc2[128];

    const int tid  = threadIdx.x;
    const int lane = tid & 63;
    const int w    = tid >> 6;
    const int l15  = lane & 15;
    const int g    = lane >> 4;
    const int e0   = blockIdx.x * 64;
    const int ne   = min(64, E - e0);

    if (tid < 64) {
        int ec = (tid < ne) ? tid : (ne - 1);
        s_row[tid] = ei[e0 + ec];
        s_col[tid] = ei[E + e0 + ec];
    }
    if (tid < 128) { s_wg[tid] = Wg[tid]; s_wc2[tid] = Wc2[tid]; }
    __syncthreads();

    if (tid < 64) {
        int r = s_row[tid], c = s_col[tid];
        float dx = x[c * 3 + 0] - x[r * 3 + 0];
        float dy = x[c * 3 + 1] - x[r * 3 + 1];
        float dz = x[c * 3 + 2] - x[r * 3 + 2];
        s_cd[tid][0] = dx; s_cd[tid][1] = dy; s_cd[tid][2] = dz;
        s_dist[tid] = sqrtf(dx * dx + dy * dy + dz * dz);
    }
    // stage A1 = [h[col] | h[row]] bf16, swizzled, rows of 512B
    #pragma unroll
    for (int it = 0; it < 16; ++it) {
        int cidx = tid + 256 * it;           // 4096 chunks of 4 floats
        int e = cidx >> 6, q = cidx & 63;
        int node = (q < 32) ? s_col[e] : s_row[e];
        float4 v = *(const float4*)&h[(size_t)node * HID + (size_t)(q & 31) * 4];
        uint2 pk;
        pk.x = (unsigned)f2bf(v.x) | ((unsigned)f2bf(v.y) << 16);
        pk.y = (unsigned)f2bf(v.z) | ((unsigned)f2bf(v.w) << 16);
        *(uint2*)((char*)sA + e * 512 + ((q * 8) ^ ((e & 7) << 4))) = pk;
    }
    __syncthreads();

    // ---- L1: A1[64x256] @ We1 (+ dist * We1[256] + be1), silu -> act1 (sB)
    {
        f32x4 acc[4][2];
        float b0 = be1[w * 32 + l15], b1 = be1[w * 32 + 16 + l15];
        #pragma unroll
        for (int rf = 0; rf < 4; ++rf) {
            acc[rf][0] = f32x4{b0, b0, b0, b0};
            acc[rf][1] = f32x4{b1, b1, b1, b1};
        }
        #pragma unroll
        for (int kc = 0; kc < 8; ++kc) {
            bf16x8 B0 = *(const bf16x8*)(We1p + (((size_t)(2 * w) * 8 + kc) * 64 + lane) * 8);
            bf16x8 B1 = *(const bf16x8*)(We1p + (((size_t)(2 * w + 1) * 8 + kc) * 64 + lane) * 8);
            #pragma unroll
            for (int rf = 0; rf < 4; ++rf) {
                int e = rf * 16 + l15, sw = (e & 7) << 4;
                const char* pr = (const char*)sA + e * 512;
                int kb = kc * 64 + g * 8;
                uint2 lo = *(const uint2*)(pr + ((kb     ) ^ sw));
                uint2 hi = *(const uint2*)(pr + ((kb + 32) ^ sw));
                bf16x8 a; ((uint2*)&a)[0] = lo; ((uint2*)&a)[1] = hi;
                acc[rf][0] = __builtin_amdgcn_mfma_f32_16x16x32_bf16(a, B0, acc[rf][0], 0, 0, 0);
                acc[rf][1] = __builtin_amdgcn_mfma_f32_16x16x32_bf16(a, B1, acc[rf][1], 0, 0, 0);
            }
        }
        float w0 = We1[(size_t)256 * HID + w * 32 + l15];
        float w1 = We1[(size_t)256 * HID + w * 32 + 16 + l15];
        #pragma unroll
        for (int rf = 0; rf < 4; ++rf)
        #pragma unroll
        for (int r = 0; r < 4; ++r) {
            int e = rf * 16 + g * 4 + r, sw = (e & 7) << 4;
            char* pd = (char*)sB + e * 256;
            float d = s_dist[e];
            *(unsigned short*)(pd + ((2 * (w * 32 + l15)) ^ sw))      = f2bf(silu_f(acc[rf][0][r] + d * w0));
            *(unsigned short*)(pd + ((2 * (w * 32 + 16 + l15)) ^ sw)) = f2bf(silu_f(acc[rf][1][r] + d * w1));
        }
    }
    __syncthreads();

    // ---- L2: act1 @ We2 + be2, silu -> act2 (sA low 16K)
    short* act1  = sB;
    short* act2  = sA;
    short* act2g = sA + 64 * 128;
    mfma_layer128(act1, We2p, be2, act2, w, lane);
    __syncthreads();

    // ---- gate
    {
        float sg = dot128(act2, s_wg, w, lane);
        if (g == 0) s_gate[w * 16 + l15] = sigmoid_f(sg + bg[0]);
    }
    __syncthreads();

    // ---- apply gate: scatter m_aggr (f32 atomics) + build act2g (bf16)
    #pragma unroll
    for (int it = 0; it < 32; ++it) {
        int idx = tid + 256 * it;
        int e = idx >> 7, f = idx & 127, sw = (e & 7) << 4;
        int off = e * 256 + ((2 * f) ^ sw);
        float val = bf2f(*(const unsigned short*)((const char*)act2 + off)) * s_gate[e];
        *(unsigned short*)((char*)act2g + off) = f2bf(val);
        if (e < ne) atomicAdd(&m_aggr[(size_t)s_col[e] * HID + f], val);
    }
    __syncthreads();

    // ---- L3: act2g @ Wc1 + bc1, silu -> act3 (sB)
    mfma_layer128(act2g, Wc1p, bc1, sB, w, lane);
    __syncthreads();

    // ---- coord weight + scatter
    {
        float cw = dot128(sB, s_wc2, w, lane) + bc2[0];
        int e = w * 16 + l15;
        if (g == 0 && e < ne) {
            int c = s_col[e];
            atomicAdd(&coord_aggr[c * 3 + 0], s_cd[e][0] * cw);
            atomicAdd(&coord_aggr[c * 3 + 1], s_cd[e][1] * cw);
            atomicAdd(&coord_aggr[c * 3 + 2], s_cd[e][2] * cw);
        }
    }
}

// ---------------------------------------------------------------------------
// Node kernel (unchanged fp32 VALU version from R0)
// ---------------------------------------------------------------------------
__global__ __launch_bounds__(256) void egnn_node_kernel(
    const float* __restrict__ h, const float* __restrict__ x,
    const float* __restrict__ m_aggr, const float* __restrict__ coord_aggr,
    const float* __restrict__ Wn1, const float* __restrict__ bn1,
    const float* __restrict__ Wn2, const float* __restrict__ bn2,
    float* __restrict__ h_out, float* __restrict__ x_out, int N)
{
    __shared__ float s_in[TILE_N][256];
    __shared__ float s_t[TILE_N][HID];

    const int tid = threadIdx.x;
    const int n0  = blockIdx.x * TILE_N;
    const int nn  = min(TILE_N, N - n0);

    if (tid < TILE_N * 3) {
        int n = tid / 3, d = tid % 3;
        if (n < nn) {
            size_t gi = (size_t)(n0 + n) * 3 + d;
            x_out[gi] = x[gi] + coord_aggr[gi];
        }
    }
    for (int idx = tid; idx < TILE_N * 256; idx += 256) {
        int n = idx >> 8, k = idx & 255;
        int ng = n0 + ((n < nn) ? n : 0);
        s_in[n][k] = (k < HID) ? h[(size_t)ng * HID + k]
                               : m_aggr[(size_t)ng * HID + (k - HID)];
    }
    __syncthreads();

    const int f    = tid & (HID - 1);
    const int half = tid >> 7;
    const int NPT  = TILE_N / 2;
    const int nb   = half * NPT;
    float acc[TILE_N / 2];

    {
        float b = bn1[f];
        #pragma unroll
        for (int i = 0; i < NPT; ++i) acc[i] = b;
        for (int k = 0; k < 256; k += 4) {
            float w0 = Wn1[(k + 0) * HID + f];
            float w1 = Wn1[(k + 1) * HID + f];
            float w2 = Wn1[(k + 2) * HID + f];
            float w3 = Wn1[(k + 3) * HID + f];
            #pragma unroll
            for (int i = 0; i < NPT; ++i) {
                float4 v = *(const float4*)&s_in[nb + i][k];
                acc[i] += v.x * w0 + v.y * w1 + v.z * w2 + v.w * w3;
            }
        }
        #pragma unroll
        for (int i = 0; i < NPT; ++i)
            s_t[nb + i][f] = silu_f(acc[i]);
    }
    __syncthreads();
    {
        float b = bn2[f];
        #pragma unroll
        for (int i = 0; i < NPT; ++i) acc[i] = b;
        for (int k = 0; k < HID; k += 4) {
            float w0 = Wn2[(k + 0) * HID + f];
            float w1 = Wn2[(k + 1) * HID + f];
            float w2 = Wn2[(k + 2) * HID + f];
            float w3 = Wn2[(k + 3) * HID + f];
            #pragma unroll
            for (int i = 0; i < NPT; ++i) {
                float4 v = *(const float4*)&s_t[nb + i][k];
                acc[i] += v.x * w0 + v.y * w1 + v.z * w2 + v.w * w3;
            }
        }
        #pragma unroll
        for (int i = 0; i < NPT; ++i) {
            int n = nb + i;
            if (n < nn)
                h_out[(size_t)(n0 + n) * HID + f] = s_in[n][f] + acc[i];
        }
    }
}

extern "C" void kernel_launch(void* const* d_in, const int* in_sizes, int n_in,
                              void* d_out, int out_size, void* d_ws, size_t ws_size,
                              hipStream_t stream) {
    const float* h   = (const float*)d_in[0];
    const float* x   = (const float*)d_in[1];
    const int*   ei  = (const int*)d_in[2];
    const float* We1 = (const float*)d_in[3];
    const float* be1 = (const float*)d_in[4];
    const float* We2 = (const float*)d_in[5];
    const float* be2 = (const float*)d_in[6];
    const float* Wg  = (const float*)d_in[7];
    const float* bg  = (const float*)d_in[8];
    const float* Wn1 = (const float*)d_in[9];
    const float* bn1 = (const float*)d_in[10];
    const float* Wn2 = (const float*)d_in[11];
    const float* bn2 = (const float*)d_in[12];
    const float* Wc1 = (const float*)d_in[13];
    const float* bc1 = (const float*)d_in[14];
    const float* Wc2 = (const float*)d_in[15];
    const float* bc2 = (const float*)d_in[16];

    const int N = in_sizes[0] / HID;
    const int E = in_sizes[2] / 2;

    float* m_aggr     = (float*)d_ws;
    float* coord_aggr = m_aggr + (size_t)N * HID;
    short* We1p       = (short*)(coord_aggr + (size_t)N * 3);   // 256*128 bf16
    short* We2p       = We1p + 256 * 128;                       // 128*128
    short* Wc1p       = We2p + 128 * 128;                       // 128*128

    hipMemsetAsync(d_ws, 0, (size_t)N * (HID + 3) * sizeof(float), stream);

    float* h_out = (float*)d_out;
    float* x_out = h_out + (size_t)N * HID;

    egnn_prep<<<dim3(32), dim3(256), 0, stream>>>(We1, We2, Wc1, We1p, We2p, Wc1p);
    egnn_edge_mfma<<<dim3((E + 63) / 64), dim3(256), 0, stream>>>(
        h, x, ei, E, We1p, We1, be1, We2p, be2, Wg, bg, Wc1p, bc1, Wc2, bc2,
        m_aggr, coord_aggr);
    egnn_node_kernel<<<dim3((N + TILE_N - 1) / TILE_N), dim3(256), 0, stream>>>(
        h, x, m_aggr, coord_aggr, Wn1, bn1, Wn2, bn2, h_out, x_out, N);
}